// Round 1
// 2777.094 us; speedup vs baseline: 1.6694x; 1.6694x over previous
//
#include <hip/hip_runtime.h>

#define D_MODEL 1024
#define SEQ     512
#define NBATCH  4
#define NHEAD   16
#define HDIM    64
#define NTOK    2048          // NBATCH*SEQ
#define VOCAB   32000
#define FFDIM   4096
#define VCHUNK  6400          // vocab chunk for logits (5 chunks)
#define MiB     (1024*1024)

typedef _Float16 f16;
typedef f16   f16x8 __attribute__((ext_vector_type(8)));
typedef float f32x4 __attribute__((ext_vector_type(4)));

// async 16B global->LDS copy (direct-to-shared DMA)
__device__ __forceinline__ void async_cp16(f16* lds, const f16* g) {
    __builtin_amdgcn_global_load_lds(
        (const __attribute__((address_space(1))) unsigned int*)g,
        (__attribute__((address_space(3))) unsigned int*)lds, 16, 0, 0);
}

// ---------------- block reduction helpers (256 threads = 4 waves) ----------
__device__ __forceinline__ float block_sum(float v, float* lds) {
    #pragma unroll
    for (int o = 1; o < 64; o <<= 1) v += __shfl_xor(v, o);
    int w = threadIdx.x >> 6;
    if ((threadIdx.x & 63) == 0) lds[w] = v;
    __syncthreads();
    v = lds[0] + lds[1] + lds[2] + lds[3];
    __syncthreads();
    return v;
}
__device__ __forceinline__ float block_max(float v, float* lds) {
    #pragma unroll
    for (int o = 1; o < 64; o <<= 1) v = fmaxf(v, __shfl_xor(v, o));
    int w = threadIdx.x >> 6;
    if ((threadIdx.x & 63) == 0) lds[w] = v;
    __syncthreads();
    v = fmaxf(fmaxf(lds[0], lds[1]), fmaxf(lds[2], lds[3]));
    __syncthreads();
    return v;
}

// ---------------- fp32 -> fp16 convert -------------------------------------
__global__ __launch_bounds__(256) void f32_to_f16_kernel(
    const float* __restrict__ in, f16* __restrict__ out, int n)
{
    int i0 = blockIdx.x * 1024 + threadIdx.x;
    #pragma unroll
    for (int e = 0; e < 4; e++) {
        int i = i0 + e * 256;
        if (i < n) out[i] = (f16)in[i];
    }
}

// ---------------- embedding + sinusoidal posenc (f32 + f16 out) ------------
__global__ __launch_bounds__(256) void embed_kernel(
    const int* __restrict__ text, const float* __restrict__ We,
    float* __restrict__ X, f16* __restrict__ X16)
{
    int t = blockIdx.x;            // token row 0..2047
    int s = t & (SEQ - 1);         // position in sequence
    int tok = text[t];
    int tid = threadIdx.x;
    const float kf = 9.210340371976184f / 1024.f;   // ln(10000)/D
    #pragma unroll
    for (int e = 0; e < 4; e++) {
        int d = tid + e * 256;
        int i2 = d & ~1;
        float freq = expf(-(float)i2 * kf);
        float ang = (float)s * freq;
        float pe = (d & 1) ? cosf(ang) : sinf(ang);
        float v = We[(size_t)tok * D_MODEL + d] + pe;
        X[(size_t)t * D_MODEL + d] = v;
        X16[(size_t)t * D_MODEL + d] = (f16)v;
    }
}

// ---------------- fp16 MFMA GEMM: C(M,N)=A(M,K)@W(N,K)^T + bias ------------
// BMx128 tile (BM = 128 or 64), BK=32, 256 threads = 4 waves (2x2), each
// wave computes (BM/2)x64.  OUTMODE: 0 = f32 out, 1 = f16 out.
// QKV3: bias selected from 3 pointers by col>>10 (fused QKV projection).
template<bool RELU, int OUTMODE, int BM, bool QKV3>
__global__ __launch_bounds__(256) void gemm16_kernel(
    const f16* __restrict__ A, const f16* __restrict__ W,
    const float* __restrict__ bias, const float* __restrict__ bias2,
    const float* __restrict__ bias3,
    float* __restrict__ C, f16* __restrict__ C16, int M, int N, int K)
{
    constexpr int AM = BM / 2;     // wave M span
    constexpr int TM = AM / 16;    // 16x16 tiles per wave in M
    __shared__ __align__(16) f16 As[BM * 32];
    __shared__ __align__(16) f16 Bs[128 * 32];
    const int tid  = threadIdx.x;
    const int lane = tid & 63;
    const int wv   = tid >> 6;
    const int wr   = (wv >> 1) * AM;
    const int wc   = (wv & 1) * 64;
    const int m0 = blockIdx.y * BM;
    const int n0 = blockIdx.x * 128;
    const int lm = lane & 15;
    const int lk = (lane >> 4) * 8;

    f32x4 acc[TM][4] = {};

    for (int k0 = 0; k0 < K; k0 += 32) {
        #pragma unroll
        for (int e = 0; e < BM / 64; e++) {
            int s = tid + e * 256;
            int row = s >> 2, cb = s & 3;
            async_cp16(&As[s * 8], &A[(size_t)(m0 + row) * K + k0 + cb * 8]);
        }
        #pragma unroll
        for (int e = 0; e < 2; e++) {
            int s = tid + e * 256;
            int row = s >> 2, cb = s & 3;
            async_cp16(&Bs[s * 8], &W[(size_t)(n0 + row) * K + k0 + cb * 8]);
        }
        __syncthreads();
        f16x8 af[TM], bfr[4];
        #pragma unroll
        for (int i = 0; i < TM; i++)
            af[i]  = *(const f16x8*)&As[(wr + i * 16 + lm) * 32 + lk];
        #pragma unroll
        for (int j = 0; j < 4; j++)
            bfr[j] = *(const f16x8*)&Bs[(wc + j * 16 + lm) * 32 + lk];
        #pragma unroll
        for (int i = 0; i < TM; i++)
            #pragma unroll
            for (int j = 0; j < 4; j++)
                acc[i][j] = __builtin_amdgcn_mfma_f32_16x16x32_f16(
                    af[i], bfr[j], acc[i][j], 0, 0, 0);
        __syncthreads();
    }

    const int rq = (lane >> 4) * 4;
    #pragma unroll
    for (int i = 0; i < TM; i++) {
        #pragma unroll
        for (int j = 0; j < 4; j++) {
            int col = n0 + wc + j * 16 + lm;
            float bj;
            if (QKV3) {
                const float* bp = col < 1024 ? bias : (col < 2048 ? bias2 : bias3);
                bj = bp[col & 1023];
            } else {
                bj = bias[col];
            }
            #pragma unroll
            for (int r = 0; r < 4; r++) {
                int row = m0 + wr + i * 16 + rq + r;
                float v = acc[i][j][r] + bj;
                if (RELU) v = fmaxf(v, 0.f);
                if (OUTMODE == 0) C[(size_t)row * N + col] = v;
                else              C16[(size_t)row * N + col] = (f16)v;
            }
        }
    }
}

// ---------------- MFMA attention scores ------------------------------------
// Per bh: Sc[q,k] = (Q[q,:] . K[k,:]) * 0.125 (+causal mask), f16 in, f32 out.
// 128x128 tile, K=64 staged in one shot (LDS layout split as [2][128][32]).
template<int CAUSAL>
__global__ __launch_bounds__(256) void attn_scores16_kernel(
    const f16* __restrict__ Qb, const f16* __restrict__ Kb,
    float* __restrict__ Sc, int ldq, int ldk, int qoff, int koff)
{
    const int bh = blockIdx.z;
    const int b = bh >> 4, h = bh & 15;
    const int q0 = blockIdx.y * 128, k0 = blockIdx.x * 128;
    const int tid = threadIdx.x;
    float* out = Sc + (size_t)bh * SEQ * SEQ;

    if (CAUSAL && k0 >= q0 + 128) {          // fully masked tile: fast fill
        const f32x4 mv = {-1e30f, -1e30f, -1e30f, -1e30f};
        #pragma unroll
        for (int e = 0; e < 16; e++) {
            int idx = tid + e * 256;          // 128x32 float4
            int rr = idx >> 5, c4 = (idx & 31) * 4;
            *(f32x4*)&out[(size_t)(q0 + rr) * SEQ + k0 + c4] = mv;
        }
        return;
    }

    __shared__ __align__(16) f16 As[128 * 64];
    __shared__ __align__(16) f16 Bs[128 * 64];
    const f16* Qg = Qb + (size_t)(b * SEQ + q0) * ldq + qoff + h * HDIM;
    const f16* Kg = Kb + (size_t)(b * SEQ + k0) * ldk + koff + h * HDIM;
    #pragma unroll
    for (int e = 0; e < 4; e++) {
        int s = tid + e * 256;                // 0..1023
        int ks = s >> 9, row = (s >> 2) & 127, cb = s & 3;
        async_cp16(&As[s * 8], &Qg[(size_t)row * ldq + ks * 32 + cb * 8]);
        async_cp16(&Bs[s * 8], &Kg[(size_t)row * ldk + ks * 32 + cb * 8]);
    }
    __syncthreads();

    const int lane = tid & 63;
    const int wv   = tid >> 6;
    const int wr   = (wv >> 1) * 64;
    const int wc   = (wv & 1) * 64;
    const int lm   = lane & 15;
    const int lk   = (lane >> 4) * 8;
    f32x4 acc[4][4] = {};
    #pragma unroll
    for (int ks = 0; ks < 2; ks++) {
        f16x8 af[4], bf[4];
        #pragma unroll
        for (int i = 0; i < 4; i++)
            af[i] = *(const f16x8*)&As[ks * 4096 + (wr + i * 16 + lm) * 32 + lk];
        #pragma unroll
        for (int j = 0; j < 4; j++)
            bf[j] = *(const f16x8*)&Bs[ks * 4096 + (wc + j * 16 + lm) * 32 + lk];
        #pragma unroll
        for (int i = 0; i < 4; i++)
            #pragma unroll
            for (int j = 0; j < 4; j++)
                acc[i][j] = __builtin_amdgcn_mfma_f32_16x16x32_f16(
                    af[i], bf[j], acc[i][j], 0, 0, 0);
    }

    const int rq = (lane >> 4) * 4;
    #pragma unroll
    for (int i = 0; i < 4; i++)
        #pragma unroll
        for (int j = 0; j < 4; j++)
            #pragma unroll
            for (int r = 0; r < 4; r++) {
                int qq = q0 + wr + i * 16 + rq + r;
                int kk = k0 + wc + j * 16 + lm;
                float v = acc[i][j][r] * 0.125f;   // 1/sqrt(64)
                if (CAUSAL && kk > qq) v = -1e30f;
                out[(size_t)qq * SEQ + kk] = v;
            }
}

// ---------------- row softmax over 512: f32 in, f16 probs out --------------
__global__ __launch_bounds__(256) void softmax_row_kernel(
    const float* __restrict__ Sc, f16* __restrict__ P)
{
    __shared__ float lds[4];
    size_t row = blockIdx.x;
    const float* p = Sc + row * SEQ;
    int tid = threadIdx.x;
    float v0 = p[tid], v1 = p[tid + 256];
    float m = block_max(fmaxf(v0, v1), lds);
    float e0 = expf(v0 - m), e1 = expf(v1 - m);
    float s = block_sum(e0 + e1, lds);
    float inv = 1.f / s;
    f16* q = P + row * SEQ;
    q[tid]       = (f16)(e0 * inv);
    q[tid + 256] = (f16)(e1 * inv);
}

// ---------------- MFMA AV: O[q,d] = P[q,:] @ V[:,d] (Vt pre-transposed) ----
// Per bh: M=512, N=64(HDIM), K=512.  64x64 tile, 4 waves 2x2 each 32x32.
__global__ __launch_bounds__(256) void attn_av16_kernel(
    const f16* __restrict__ P, const f16* __restrict__ Vt,
    f16* __restrict__ O16)
{
    __shared__ __align__(16) f16 Ps[64 * 32];
    __shared__ __align__(16) f16 Vs[64 * 32];
    const int bh = blockIdx.y;
    const int b = bh >> 4, h = bh & 15;
    const int q0 = blockIdx.x * 64;
    const int tid  = threadIdx.x;
    const int lane = tid & 63;
    const int wv   = tid >> 6;
    const int wr   = (wv >> 1) * 32;
    const int wc   = (wv & 1) * 32;
    const int lm   = lane & 15;
    const int lk   = (lane >> 4) * 8;
    const f16* Pg = P  + ((size_t)bh * SEQ + q0) * SEQ;  // [64][512]
    const f16* Vg = Vt + (size_t)bh * HDIM * SEQ;        // [64][512]

    f32x4 acc[2][2] = {};
    for (int k0 = 0; k0 < SEQ; k0 += 32) {
        int row = tid >> 2, cb = tid & 3;
        async_cp16(&Ps[tid * 8], &Pg[(size_t)row * SEQ + k0 + cb * 8]);
        async_cp16(&Vs[tid * 8], &Vg[(size_t)row * SEQ + k0 + cb * 8]);
        __syncthreads();
        f16x8 af[2], bf[2];
        #pragma unroll
        for (int i = 0; i < 2; i++)
            af[i] = *(const f16x8*)&Ps[(wr + i * 16 + lm) * 32 + lk];
        #pragma unroll
        for (int j = 0; j < 2; j++)
            bf[j] = *(const f16x8*)&Vs[(wc + j * 16 + lm) * 32 + lk];
        #pragma unroll
        for (int i = 0; i < 2; i++)
            #pragma unroll
            for (int j = 0; j < 2; j++)
                acc[i][j] = __builtin_amdgcn_mfma_f32_16x16x32_f16(
                    af[i], bf[j], acc[i][j], 0, 0, 0);
        __syncthreads();
    }

    const int rq = (lane >> 4) * 4;
    #pragma unroll
    for (int i = 0; i < 2; i++)
        #pragma unroll
        for (int j = 0; j < 2; j++)
            #pragma unroll
            for (int r = 0; r < 4; r++)
                O16[(size_t)(b * SEQ + q0 + wr + i * 16 + rq + r) * D_MODEL
                    + h * HDIM + wc + j * 16 + lm] = (f16)acc[i][j][r];
}

// ---------------- V transpose: [token][ldv]@vbase+h*64 -> Vt[bh][d][s] -----
__global__ __launch_bounds__(256) void vtrans_kernel(
    const f16* __restrict__ V, f16* __restrict__ Vt, int ldv, int vbase)
{
    __shared__ __align__(16) f16 t[64][72];
    const int bh = blockIdx.y;
    const int b = bh >> 4, h = bh & 15;
    const int s0 = blockIdx.x * 64;
    const int tid = threadIdx.x;
    const int r = tid >> 3;            // 0..31
    const int c8 = (tid & 7) * 8;
    #pragma unroll
    for (int half = 0; half < 2; half++) {
        int row = r + half * 32;
        f16x8 v = *(const f16x8*)&V[(size_t)(b * SEQ + s0 + row) * ldv
                                    + vbase + h * HDIM + c8];
        #pragma unroll
        for (int j = 0; j < 8; j++) t[c8 + j][row] = v[j];
    }
    __syncthreads();
    const int d = tid >> 2;            // 0..63
    const int sblk = (tid & 3) * 16;
    f16* dst = Vt + ((size_t)bh * HDIM + d) * SEQ + s0 + sblk;
    *(f16x8*)&dst[0] = *(const f16x8*)&t[d][sblk];
    *(f16x8*)&dst[8] = *(const f16x8*)&t[d][sblk + 8];
}

// ---------------- fused residual add + LayerNorm (f32 + f16 out) -----------
__global__ __launch_bounds__(256) void add_ln_kernel(
    const float* __restrict__ X, const float* __restrict__ Y,
    const float* __restrict__ g, const float* __restrict__ bb,
    float* __restrict__ Out, f16* __restrict__ Out16)
{
    __shared__ float lds[4];
    int row = blockIdx.x;
    const float* xp = X + (size_t)row * D_MODEL;
    const float* yp = Y + (size_t)row * D_MODEL;
    int tid = threadIdx.x;
    float s[4];
    float lsum = 0.f;
    #pragma unroll
    for (int e = 0; e < 4; e++) {
        int d = tid + e * 256;
        s[e] = xp[d] + yp[d];
        lsum += s[e];
    }
    float mu = block_sum(lsum, lds) * (1.f / D_MODEL);
    float lv = 0.f;
    #pragma unroll
    for (int e = 0; e < 4; e++) { float t = s[e] - mu; lv += t * t; }
    float rstd = rsqrtf(block_sum(lv, lds) * (1.f / D_MODEL) + 1e-5f);
    #pragma unroll
    for (int e = 0; e < 4; e++) {
        int d = tid + e * 256;
        float v = (s[e] - mu) * rstd * g[d] + bb[d];
        Out[(size_t)row * D_MODEL + d] = v;
        Out16[(size_t)row * D_MODEL + d] = (f16)v;
    }
}

// ---------------- softmax over axis 0 (batch of 4), vocab-chunked ----------
__global__ __launch_bounds__(256) void softmax_axis0_chunk_kernel(
    const float* __restrict__ L, float* __restrict__ out, int cv0)
{
    int idx = blockIdx.x * 256 + threadIdx.x;     // over SEQ*VCHUNK
    if (idx >= SEQ * VCHUNK) return;
    int s = idx / VCHUNK;
    int c = idx - s * VCHUNK;
    float v0 = L[((size_t)(0 * SEQ + s)) * VCHUNK + c];
    float v1 = L[((size_t)(1 * SEQ + s)) * VCHUNK + c];
    float v2 = L[((size_t)(2 * SEQ + s)) * VCHUNK + c];
    float v3 = L[((size_t)(3 * SEQ + s)) * VCHUNK + c];
    float m = fmaxf(fmaxf(v0, v1), fmaxf(v2, v3));
    float e0 = expf(v0 - m), e1 = expf(v1 - m), e2 = expf(v2 - m), e3 = expf(v3 - m);
    float inv = 1.f / (e0 + e1 + e2 + e3);
    out[((size_t)(0 * SEQ + s)) * VOCAB + cv0 + c] = e0 * inv;
    out[((size_t)(1 * SEQ + s)) * VOCAB + cv0 + c] = e1 * inv;
    out[((size_t)(2 * SEQ + s)) * VOCAB + cv0 + c] = e2 * inv;
    out[((size_t)(3 * SEQ + s)) * VOCAB + cv0 + c] = e3 * inv;
}

// ===========================================================================
extern "C" void kernel_launch(void* const* d_in, const int* in_sizes, int n_in,
                              void* d_out, int out_size, void* d_ws, size_t ws_size,
                              hipStream_t stream)
{
    const int*   text = (const int*)d_in[0];
    const float* enc  = (const float*)d_in[1];
    const float* W_e  = (const float*)d_in[2];
    const float* b_out= (const float*)d_in[3];
    const float* ln_g = (const float*)d_in[4];
    const float* ln_b = (const float*)d_in[5];
    const float* W1   = (const float*)d_in[6];
    const float* b1   = (const float*)d_in[7];
    const float* W2   = (const float*)d_in[8];
    const float* b2   = (const float*)d_in[9];
    const float* mWq  = (const float*)d_in[10]; const float* mbq = (const float*)d_in[11];
    const float* mWk  = (const float*)d_in[12]; const float* mbk = (const float*)d_in[13];
    const float* mWv  = (const float*)d_in[14]; const float* mbv = (const float*)d_in[15];
    const float* mWo  = (const float*)d_in[16]; const float* mbo = (const float*)d_in[17];
    const float* cWq  = (const float*)d_in[18]; const float* cbq = (const float*)d_in[19];
    const float* cWk  = (const float*)d_in[20]; const float* cbk = (const float*)d_in[21];
    const float* cWv  = (const float*)d_in[22]; const float* cbv = (const float*)d_in[23];
    const float* cWo  = (const float*)d_in[24]; const float* cbo = (const float*)d_in[25];
    float* out = (float*)d_out;

    // ---- workspace layout (250.5 MiB total; 258 MiB proven available) ----
    // f32: x(8) a(8) c(8) | Sc(64, logits(50) alias, o(8) aliases Sc[56:64])
    // scratch(32): P16 / ffh16 / {cWk16s,cWv16s,enc16 at startup}
    char* w8 = (char*)d_ws;
    float* x    = (float*)(w8 +   0 * (size_t)MiB);
    float* a    = (float*)(w8 +   8 * (size_t)MiB);
    float* c    = (float*)(w8 +  16 * (size_t)MiB);
    float* Sc   = (float*)(w8 +  24 * (size_t)MiB);   // 64 MiB
    float* o    = (float*)(w8 +  80 * (size_t)MiB);   // = Sc + 56 MiB (dead overlap)
    float* logits = Sc;                               // 50 MiB, after last attn
    char* scratch = w8 + 88 * (size_t)MiB;            // 32 MiB
    f16* P16    = (f16*)scratch;                      // probs (32 MiB), attn phases
    f16* ffh16  = (f16*)scratch;                      // FFN hidden (16 MiB), FFN phase
    f16* cWk16s = (f16*)scratch;                      // startup only
    f16* cWv16s = (f16*)(scratch + 2 * (size_t)MiB);  // startup only
    f16* enc16  = (f16*)(scratch + 4 * (size_t)MiB);  // startup only (4 MiB)
    f16* qkv16  = (f16*)(w8 + 120 * (size_t)MiB);     // 12 MiB [2048][3072]
    f16* q16    = qkv16;                              // cross-Q reuses (4 MiB)
    f16* vt16   = (f16*)(w8 + 132 * (size_t)MiB);     // 4 MiB  [bh][64][512]
    f16* enck16 = (f16*)(w8 + 136 * (size_t)MiB);     // 4 MiB
    f16* encvt16= (f16*)(w8 + 140 * (size_t)MiB);     // 4 MiB
    f16* attn16 = (f16*)(w8 + 144 * (size_t)MiB);     // 4 MiB (also encV tmp)
    f16* x16    = (f16*)(w8 + 148 * (size_t)MiB);
    f16* a16    = (f16*)(w8 + 152 * (size_t)MiB);
    f16* c16    = (f16*)(w8 + 156 * (size_t)MiB);
    f16* mQKV16 = (f16*)(w8 + 160 * (size_t)MiB);     // 6 MiB = Wq|Wk|Wv rows
    f16* mWo16  = (f16*)(w8 + 166 * (size_t)MiB);
    f16* cWq16  = (f16*)(w8 + 168 * (size_t)MiB);
    f16* cWo16  = (f16*)(w8 + 170 * (size_t)MiB);
    f16* W116   = (f16*)(w8 + 172 * (size_t)MiB);     // 8 MiB
    f16* W216   = (f16*)(w8 + 180 * (size_t)MiB);     // 8 MiB
    f16* We16   = (f16*)(w8 + 188 * (size_t)MiB);     // 62.5 MiB

    auto conv = [&](const float* src, f16* dst, int n) {
        f32_to_f16_kernel<<<(n + 1023) / 1024, 256, 0, stream>>>(src, dst, n);
    };

    // ---- weight / encoder conversion (every call; graph-safe) ----
    const int DD = D_MODEL * D_MODEL;
    conv(mWq, mQKV16, DD);
    conv(mWk, mQKV16 + (size_t)DD, DD);
    conv(mWv, mQKV16 + 2 * (size_t)DD, DD);
    conv(mWo, mWo16, DD);
    conv(cWq, cWq16, DD); conv(cWk, cWk16s, DD); conv(cWv, cWv16s, DD); conv(cWo, cWo16, DD);
    conv(W1, W116, FFDIM * D_MODEL); conv(W2, W216, FFDIM * D_MODEL);
    conv(W_e, We16, VOCAB * D_MODEL);
    conv(enc, enc16, NTOK * D_MODEL);

    // ---- embed + posenc ----
    embed_kernel<<<NTOK, 256, 0, stream>>>(text, W_e, x, x16);

    // ---- encoder K (f16) and V^T (fixed across layers) ----
    gemm16_kernel<false, 1, 64, false><<<dim3(D_MODEL / 128, NTOK / 64), 256, 0, stream>>>(
        enc16, cWk16s, cbk, nullptr, nullptr, nullptr, enck16, NTOK, D_MODEL, D_MODEL);
    gemm16_kernel<false, 1, 64, false><<<dim3(D_MODEL / 128, NTOK / 64), 256, 0, stream>>>(
        enc16, cWv16s, cbv, nullptr, nullptr, nullptr, attn16, NTOK, D_MODEL, D_MODEL);
    vtrans_kernel<<<dim3(SEQ / 64, NBATCH * NHEAD), 256, 0, stream>>>(
        attn16, encvt16, D_MODEL, 0);

    const int BH = NBATCH * NHEAD;   // 64
    for (int layer = 0; layer < 6; layer++) {
        // --- self attention (causal), fused QKV: N=3072, 768 WGs ---
        gemm16_kernel<false, 1, 64, true><<<dim3(3072 / 128, NTOK / 64), 256, 0, stream>>>(
            x16, mQKV16, mbq, mbk, mbv, nullptr, qkv16, NTOK, 3072, D_MODEL);
        vtrans_kernel<<<dim3(SEQ / 64, BH), 256, 0, stream>>>(qkv16, vt16, 3072, 2048);
        attn_scores16_kernel<1><<<dim3(SEQ / 128, SEQ / 128, BH), 256, 0, stream>>>(
            qkv16, qkv16, Sc, 3072, 3072, 0, 1024);
        softmax_row_kernel<<<BH * SEQ, 256, 0, stream>>>(Sc, P16);
        attn_av16_kernel<<<dim3(SEQ / 64, BH), 256, 0, stream>>>(P16, vt16, attn16);
        gemm16_kernel<false, 0, 64, false><<<dim3(D_MODEL / 128, NTOK / 64), 256, 0, stream>>>(
            attn16, mWo16, mbo, nullptr, nullptr, o, nullptr, NTOK, D_MODEL, D_MODEL);
        add_ln_kernel<<<NTOK, 256, 0, stream>>>(x, o, ln_g, ln_b, a, a16);

        // --- cross attention ---
        gemm16_kernel<false, 1, 64, false><<<dim3(D_MODEL / 128, NTOK / 64), 256, 0, stream>>>(
            a16, cWq16, cbq, nullptr, nullptr, nullptr, q16, NTOK, D_MODEL, D_MODEL);
        attn_scores16_kernel<0><<<dim3(SEQ / 128, SEQ / 128, BH), 256, 0, stream>>>(
            q16, enck16, Sc, D_MODEL, D_MODEL, 0, 0);
        softmax_row_kernel<<<BH * SEQ, 256, 0, stream>>>(Sc, P16);
        attn_av16_kernel<<<dim3(SEQ / 64, BH), 256, 0, stream>>>(P16, encvt16, attn16);
        gemm16_kernel<false, 0, 64, false><<<dim3(D_MODEL / 128, NTOK / 64), 256, 0, stream>>>(
            attn16, cWo16, cbo, nullptr, nullptr, o, nullptr, NTOK, D_MODEL, D_MODEL);
        add_ln_kernel<<<NTOK, 256, 0, stream>>>(o, a, ln_g, ln_b, c, c16);

        // --- FFN ---
        gemm16_kernel<true, 1, 128, false><<<dim3(FFDIM / 128, NTOK / 128), 256, 0, stream>>>(
            c16, W116, b1, nullptr, nullptr, nullptr, ffh16, NTOK, FFDIM, D_MODEL);
        gemm16_kernel<false, 0, 64, false><<<dim3(D_MODEL / 128, NTOK / 64), 256, 0, stream>>>(
            ffh16, W216, b2, nullptr, nullptr, o, nullptr, NTOK, D_MODEL, FFDIM);
        add_ln_kernel<<<NTOK, 256, 0, stream>>>(c, o, ln_g, ln_b, x, x16);
    }

    // ---- final logits (vocab-chunked) + axis-0 softmax ----
    for (int ch = 0; ch < VOCAB / VCHUNK; ch++) {
        int cv0 = ch * VCHUNK;
        gemm16_kernel<false, 0, 128, false><<<dim3(VCHUNK / 128, NTOK / 128), 256, 0, stream>>>(
            x16, We16 + (size_t)cv0 * D_MODEL, b_out + cv0, nullptr, nullptr,
            logits, nullptr, NTOK, VCHUNK, D_MODEL);
        softmax_axis0_chunk_kernel<<<(SEQ * VCHUNK + 255) / 256, 256, 0, stream>>>(
            logits, out, cv0);
    }
}

// Round 2
// 2445.239 us; speedup vs baseline: 1.8960x; 1.1357x over previous
//
#include <hip/hip_runtime.h>

#define D_MODEL 1024
#define SEQ     512
#define NBATCH  4
#define NHEAD   16
#define HDIM    64
#define NTOK    2048          // NBATCH*SEQ
#define VOCAB   32000
#define FFDIM   4096
#define MiB     (1024*1024)

typedef _Float16 f16;
typedef f16   f16x8 __attribute__((ext_vector_type(8)));
typedef float f32x4 __attribute__((ext_vector_type(4)));

// async 16B global->LDS copy (direct-to-shared DMA; LDS dest must be linear
// in lane order: dst = base + lane*16)
__device__ __forceinline__ void async_cp16(f16* lds, const f16* g) {
    __builtin_amdgcn_global_load_lds(
        (const __attribute__((address_space(1))) unsigned int*)g,
        (__attribute__((address_space(3))) unsigned int*)lds, 16, 0, 0);
}

// ---------------- block reduction helpers (256 threads = 4 waves) ----------
__device__ __forceinline__ float block_sum(float v, float* lds) {
    #pragma unroll
    for (int o = 1; o < 64; o <<= 1) v += __shfl_xor(v, o);
    int w = threadIdx.x >> 6;
    if ((threadIdx.x & 63) == 0) lds[w] = v;
    __syncthreads();
    v = lds[0] + lds[1] + lds[2] + lds[3];
    __syncthreads();
    return v;
}

// ---------------- fp32 -> fp16 convert -------------------------------------
__global__ __launch_bounds__(256) void f32_to_f16_kernel(
    const float* __restrict__ in, f16* __restrict__ out, int n)
{
    int i0 = blockIdx.x * 1024 + threadIdx.x;
    #pragma unroll
    for (int e = 0; e < 4; e++) {
        int i = i0 + e * 256;
        if (i < n) out[i] = (f16)in[i];
    }
}

// ---------------- embedding + sinusoidal posenc (f32 + f16 out) ------------
// One block per position s; trig computed once, shared across the 4 batches.
__global__ __launch_bounds__(256) void embed_kernel(
    const int* __restrict__ text, const float* __restrict__ We,
    float* __restrict__ X, f16* __restrict__ X16)
{
    int s = blockIdx.x;            // position 0..511
    int tid = threadIdx.x;
    int tok[NBATCH];
    #pragma unroll
    for (int b = 0; b < NBATCH; b++) tok[b] = text[b * SEQ + s];
    const float kf = 9.210340371976184f / 1024.f;   // ln(10000)/D
    #pragma unroll
    for (int e = 0; e < 4; e++) {
        int d = tid + e * 256;
        int i2 = d & ~1;
        float freq = expf(-(float)i2 * kf);
        float ang = (float)s * freq;
        float pe = (d & 1) ? cosf(ang) : sinf(ang);
        #pragma unroll
        for (int b = 0; b < NBATCH; b++) {
            float v = We[(size_t)tok[b] * D_MODEL + d] + pe;
            size_t off = (size_t)(b * SEQ + s) * D_MODEL + d;
            X[off] = v;
            X16[off] = (f16)v;
        }
    }
}

// ---------------- fp16 MFMA GEMM: C(M,N)=A(M,K)@W(N,K)^T + bias ------------
// BMx128 tile (BM = 128 or 64), BK=32, 256 threads = 4 waves (2x2), each
// wave computes (BM/2)x64.
// OUTMODE: 0 = f32 out, 1 = f16 out, 2 = softmax over r (batch axis, A rows
// interleaved s*4+b) written straight to the final output.
// QKV3: bias selected from 3 pointers by col>>10 (fused QKV projection).
template<bool RELU, int OUTMODE, int BM, bool QKV3>
__global__ __launch_bounds__(256) void gemm16_kernel(
    const f16* __restrict__ A, const f16* __restrict__ W,
    const float* __restrict__ bias, const float* __restrict__ bias2,
    const float* __restrict__ bias3,
    float* __restrict__ C, f16* __restrict__ C16, int M, int N, int K)
{
    constexpr int AM = BM / 2;     // wave M span
    constexpr int TM = AM / 16;    // 16x16 tiles per wave in M
    __shared__ __align__(16) f16 As[BM * 32];
    __shared__ __align__(16) f16 Bs[128 * 32];
    const int tid  = threadIdx.x;
    const int lane = tid & 63;
    const int wv   = tid >> 6;
    const int wr   = (wv >> 1) * AM;
    const int wc   = (wv & 1) * 64;
    const int m0 = blockIdx.y * BM;
    const int n0 = blockIdx.x * 128;
    const int lm = lane & 15;
    const int lk = (lane >> 4) * 8;

    f32x4 acc[TM][4] = {};

    for (int k0 = 0; k0 < K; k0 += 32) {
        #pragma unroll
        for (int e = 0; e < BM / 64; e++) {
            int s = tid + e * 256;
            int row = s >> 2, cb = s & 3;
            async_cp16(&As[s * 8], &A[(size_t)(m0 + row) * K + k0 + cb * 8]);
        }
        #pragma unroll
        for (int e = 0; e < 2; e++) {
            int s = tid + e * 256;
            int row = s >> 2, cb = s & 3;
            async_cp16(&Bs[s * 8], &W[(size_t)(n0 + row) * K + k0 + cb * 8]);
        }
        __syncthreads();
        f16x8 af[TM], bfr[4];
        #pragma unroll
        for (int i = 0; i < TM; i++)
            af[i]  = *(const f16x8*)&As[(wr + i * 16 + lm) * 32 + lk];
        #pragma unroll
        for (int j = 0; j < 4; j++)
            bfr[j] = *(const f16x8*)&Bs[(wc + j * 16 + lm) * 32 + lk];
        #pragma unroll
        for (int i = 0; i < TM; i++)
            #pragma unroll
            for (int j = 0; j < 4; j++)
                acc[i][j] = __builtin_amdgcn_mfma_f32_16x16x32_f16(
                    af[i], bfr[j], acc[i][j], 0, 0, 0);
        __syncthreads();
    }

    const int rq = (lane >> 4) * 4;
    #pragma unroll
    for (int i = 0; i < TM; i++) {
        #pragma unroll
        for (int j = 0; j < 4; j++) {
            int col = n0 + wc + j * 16 + lm;
            float bj;
            if (QKV3) {
                const float* bp = col < 1024 ? bias : (col < 2048 ? bias2 : bias3);
                bj = bp[col & 1023];
            } else {
                bj = bias[col];
            }
            if (OUTMODE == 2) {
                // rows are s*4+b (b = r): softmax over the 4 batch values
                int srow = (m0 + wr + i * 16 + rq) >> 2;
                float v[4];
                float mx = -1e30f;
                #pragma unroll
                for (int r = 0; r < 4; r++) {
                    v[r] = acc[i][j][r] + bj;
                    mx = fmaxf(mx, v[r]);
                }
                float ssum = 0.f;
                #pragma unroll
                for (int r = 0; r < 4; r++) { v[r] = expf(v[r] - mx); ssum += v[r]; }
                float inv = 1.f / ssum;
                #pragma unroll
                for (int r = 0; r < 4; r++)
                    C[((size_t)r * SEQ + srow) * N + col] = v[r] * inv;
            } else {
                #pragma unroll
                for (int r = 0; r < 4; r++) {
                    int row = m0 + wr + i * 16 + rq + r;
                    float v = acc[i][j][r] + bj;
                    if (RELU) v = fmaxf(v, 0.f);
                    if (OUTMODE == 0) C[(size_t)row * N + col] = v;
                    else              C16[(size_t)row * N + col] = (f16)v;
                }
            }
        }
    }
}

// ---------------- fused attention scores + row softmax ---------------------
// Per block: (64 q-rows, bh).  S row (512 cols) kept in registers
// (32 x f32x4 per lane), K staged double-buffered in LDS as [2][2][128][32].
// Writes f16 probabilities directly (zeros for causally-skipped tiles).
template<int CAUSAL>
__global__ __launch_bounds__(256) void attn_sm_kernel(
    const f16* __restrict__ Qb, const f16* __restrict__ Kb,
    f16* __restrict__ P, int ldq, int ldk, int qoff, int koff)
{
    __shared__ __align__(16) f16 Qs[2][64][32];      // 8 KB
    __shared__ __align__(16) f16 Ks[2][2][128][32];  // 32 KB
    const int bh = blockIdx.y;
    const int b = bh >> 4, h = bh & 15;
    const int q0 = blockIdx.x * 64;
    const int tid  = threadIdx.x;
    const int lane = tid & 63;
    const int w    = tid >> 6;          // wave owns rows q0+w*16 .. +15
    const int lm   = lane & 15;
    const int lk   = (lane >> 4) * 8;
    const int nkt  = CAUSAL ? (q0 >> 7) + 1 : 4;   // k-tiles of 128 to compute
    const int nj   = nkt * 8;                      // valid 16-col tiles

    const f16* Qg = Qb + (size_t)(b * SEQ + q0) * ldq + qoff + h * HDIM;
    const f16* Kg = Kb + (size_t)(b * SEQ) * ldk + koff + h * HDIM;

    // stage Q (64x64) + K-tile 0 (128x64)
    #pragma unroll
    for (int e = 0; e < 2; e++) {
        int cc = tid + e * 256;                    // 0..511
        int ks = cc >> 8, row = (cc >> 2) & 63, cb = cc & 3;
        async_cp16(&Qs[ks][row][cb * 8], &Qg[(size_t)row * ldq + ks * 32 + cb * 8]);
    }
    #pragma unroll
    for (int e = 0; e < 4; e++) {
        int cc = tid + e * 256;                    // 0..1023
        int ks = cc >> 9, row = (cc >> 2) & 127, cb = cc & 3;
        async_cp16(&Ks[0][ks][row][cb * 8], &Kg[(size_t)row * ldk + ks * 32 + cb * 8]);
    }
    __syncthreads();

    f16x8 af[2];
    af[0] = *(const f16x8*)&Qs[0][w * 16 + lm][lk];
    af[1] = *(const f16x8*)&Qs[1][w * 16 + lm][lk];

    f32x4 acc[32] = {};

    #pragma unroll
    for (int kt = 0; kt < 4; kt++) {
        if (kt < nkt) {
            if (kt + 1 < nkt) {                    // prefetch next K-tile
                const f16* src = Kg + (size_t)(kt + 1) * 128 * ldk;
                int buf = (kt + 1) & 1;
                #pragma unroll
                for (int e = 0; e < 4; e++) {
                    int cc = tid + e * 256;
                    int ks = cc >> 9, row = (cc >> 2) & 127, cb = cc & 3;
                    async_cp16(&Ks[buf][ks][row][cb * 8],
                               &src[(size_t)row * ldk + ks * 32 + cb * 8]);
                }
            }
            #pragma unroll
            for (int ks = 0; ks < 2; ks++)
                #pragma unroll
                for (int j = 0; j < 8; j++) {
                    f16x8 bf = *(const f16x8*)&Ks[kt & 1][ks][j * 16 + lm][lk];
                    acc[kt * 8 + j] = __builtin_amdgcn_mfma_f32_16x16x32_f16(
                        af[ks], bf, acc[kt * 8 + j], 0, 0, 0);
                }
            if (kt + 1 < nkt) __syncthreads();
        }
    }

    // exact row softmax; rows per lane: (lane>>4)*4 + r within this wave's 16
    const int rq = (lane >> 4) * 4;
    #pragma unroll
    for (int r = 0; r < 4; r++) {
        const int qq = q0 + w * 16 + rq + r;
        float mr = -1e30f;
        #pragma unroll
        for (int j = 0; j < 32; j++) {
            if (j < nj) {
                float v = acc[j][r] * 0.125f;      // 1/sqrt(64)
                if (CAUSAL && (j * 16 + lm) > qq) v = -1e30f;
                acc[j][r] = v;
                mr = fmaxf(mr, v);
            }
        }
        mr = fmaxf(mr, __shfl_xor(mr, 1));
        mr = fmaxf(mr, __shfl_xor(mr, 2));
        mr = fmaxf(mr, __shfl_xor(mr, 4));
        mr = fmaxf(mr, __shfl_xor(mr, 8));
        float sum = 0.f;
        #pragma unroll
        for (int j = 0; j < 32; j++) {
            if (j < nj) {
                float e = expf(acc[j][r] - mr);
                acc[j][r] = e;
                sum += e;
            }
        }
        sum += __shfl_xor(sum, 1);
        sum += __shfl_xor(sum, 2);
        sum += __shfl_xor(sum, 4);
        sum += __shfl_xor(sum, 8);
        float inv = 1.f / sum;
        f16* prow = P + ((size_t)bh * SEQ + qq) * SEQ + lm;
        #pragma unroll
        for (int j = 0; j < 32; j++) {
            float pv = (j < nj) ? acc[j][r] * inv : 0.f;
            prow[j * 16] = (f16)pv;
        }
    }
}

// ---------------- MFMA AV: O[q,d] = P[q,:] @ V[:,d] (Vt pre-transposed) ----
// Per bh: M=512, N=64(HDIM), K=512 (or q0+64 if causal: P is 0 beyond).
__global__ __launch_bounds__(256) void attn_av16_kernel(
    const f16* __restrict__ P, const f16* __restrict__ Vt,
    f16* __restrict__ O16, int causal)
{
    __shared__ __align__(16) f16 Ps[64 * 32];
    __shared__ __align__(16) f16 Vs[64 * 32];
    const int bh = blockIdx.y;
    const int b = bh >> 4, h = bh & 15;
    const int q0 = blockIdx.x * 64;
    const int tid  = threadIdx.x;
    const int lane = tid & 63;
    const int wv   = tid >> 6;
    const int wr   = (wv >> 1) * 32;
    const int wc   = (wv & 1) * 32;
    const int lm   = lane & 15;
    const int lk   = (lane >> 4) * 8;
    const f16* Pg = P  + ((size_t)bh * SEQ + q0) * SEQ;  // [64][512]
    const f16* Vg = Vt + (size_t)bh * HDIM * SEQ;        // [64][512]
    const int klim = causal ? q0 + 64 : SEQ;

    f32x4 acc[2][2] = {};
    for (int k0 = 0; k0 < klim; k0 += 32) {
        int row = tid >> 2, cb = tid & 3;
        async_cp16(&Ps[tid * 8], &Pg[(size_t)row * SEQ + k0 + cb * 8]);
        async_cp16(&Vs[tid * 8], &Vg[(size_t)row * SEQ + k0 + cb * 8]);
        __syncthreads();
        f16x8 af[2], bf[2];
        #pragma unroll
        for (int i = 0; i < 2; i++)
            af[i] = *(const f16x8*)&Ps[(wr + i * 16 + lm) * 32 + lk];
        #pragma unroll
        for (int j = 0; j < 2; j++)
            bf[j] = *(const f16x8*)&Vs[(wc + j * 16 + lm) * 32 + lk];
        #pragma unroll
        for (int i = 0; i < 2; i++)
            #pragma unroll
            for (int j = 0; j < 2; j++)
                acc[i][j] = __builtin_amdgcn_mfma_f32_16x16x32_f16(
                    af[i], bf[j], acc[i][j], 0, 0, 0);
        __syncthreads();
    }

    const int rq = (lane >> 4) * 4;
    #pragma unroll
    for (int i = 0; i < 2; i++)
        #pragma unroll
        for (int j = 0; j < 2; j++)
            #pragma unroll
            for (int r = 0; r < 4; r++)
                O16[(size_t)(b * SEQ + q0 + wr + i * 16 + rq + r) * D_MODEL
                    + h * HDIM + wc + j * 16 + lm] = (f16)acc[i][j][r];
}

// ---------------- V transpose: [token][ldv]@vbase+h*64 -> Vt[bh][d][s] -----
__global__ __launch_bounds__(256) void vtrans_kernel(
    const f16* __restrict__ V, f16* __restrict__ Vt, int ldv, int vbase)
{
    __shared__ __align__(16) f16 t[64][72];
    const int bh = blockIdx.y;
    const int b = bh >> 4, h = bh & 15;
    const int s0 = blockIdx.x * 64;
    const int tid = threadIdx.x;
    const int r = tid >> 3;            // 0..31
    const int c8 = (tid & 7) * 8;
    #pragma unroll
    for (int half = 0; half < 2; half++) {
        int row = r + half * 32;
        f16x8 v = *(const f16x8*)&V[(size_t)(b * SEQ + s0 + row) * ldv
                                    + vbase + h * HDIM + c8];
        #pragma unroll
        for (int j = 0; j < 8; j++) t[c8 + j][row] = v[j];
    }
    __syncthreads();
    const int d = tid >> 2;            // 0..63
    const int sblk = (tid & 3) * 16;
    f16* dst = Vt + ((size_t)bh * HDIM + d) * SEQ + s0 + sblk;
    *(f16x8*)&dst[0] = *(const f16x8*)&t[d][sblk];
    *(f16x8*)&dst[8] = *(const f16x8*)&t[d][sblk + 8];
}

// ---------------- fused residual add + LayerNorm (f32 + f16 out) -----------
// IL: write the f16 copy batch-interleaved (row' = s*4+b) for the fused
// logits+softmax epilogue.
template<bool IL>
__global__ __launch_bounds__(256) void add_ln_kernel(
    const float* __restrict__ X, const float* __restrict__ Y,
    const float* __restrict__ g, const float* __restrict__ bb,
    float* __restrict__ Out, f16* __restrict__ Out16)
{
    __shared__ float lds[4];
    int row = blockIdx.x;
    const float* xp = X + (size_t)row * D_MODEL;
    const float* yp = Y + (size_t)row * D_MODEL;
    int tid = threadIdx.x;
    float s[4];
    float lsum = 0.f;
    #pragma unroll
    for (int e = 0; e < 4; e++) {
        int d = tid + e * 256;
        s[e] = xp[d] + yp[d];
        lsum += s[e];
    }
    float mu = block_sum(lsum, lds) * (1.f / D_MODEL);
    float lv = 0.f;
    #pragma unroll
    for (int e = 0; e < 4; e++) { float t = s[e] - mu; lv += t * t; }
    float rstd = rsqrtf(block_sum(lv, lds) * (1.f / D_MODEL) + 1e-5f);
    int orow = IL ? ((row & (SEQ - 1)) * 4 + (row >> 9)) : row;
    #pragma unroll
    for (int e = 0; e < 4; e++) {
        int d = tid + e * 256;
        float v = (s[e] - mu) * rstd * g[d] + bb[d];
        Out[(size_t)row * D_MODEL + d] = v;
        Out16[(size_t)orow * D_MODEL + d] = (f16)v;
    }
}

// ===========================================================================
extern "C" void kernel_launch(void* const* d_in, const int* in_sizes, int n_in,
                              void* d_out, int out_size, void* d_ws, size_t ws_size,
                              hipStream_t stream)
{
    const int*   text = (const int*)d_in[0];
    const float* enc  = (const float*)d_in[1];
    const float* W_e  = (const float*)d_in[2];
    const float* b_out= (const float*)d_in[3];
    const float* ln_g = (const float*)d_in[4];
    const float* ln_b = (const float*)d_in[5];
    const float* W1   = (const float*)d_in[6];
    const float* b1   = (const float*)d_in[7];
    const float* W2   = (const float*)d_in[8];
    const float* b2   = (const float*)d_in[9];
    const float* mWq  = (const float*)d_in[10]; const float* mbq = (const float*)d_in[11];
    const float* mWk  = (const float*)d_in[12]; const float* mbk = (const float*)d_in[13];
    const float* mWv  = (const float*)d_in[14]; const float* mbv = (const float*)d_in[15];
    const float* mWo  = (const float*)d_in[16]; const float* mbo = (const float*)d_in[17];
    const float* cWq  = (const float*)d_in[18]; const float* cbq = (const float*)d_in[19];
    const float* cWk  = (const float*)d_in[20]; const float* cbk = (const float*)d_in[21];
    const float* cWv  = (const float*)d_in[22]; const float* cbv = (const float*)d_in[23];
    const float* cWo  = (const float*)d_in[24]; const float* cbo = (const float*)d_in[25];
    float* out = (float*)d_out;

    // ---- workspace layout (Sc/logits buffer no longer needed) ----
    char* w8 = (char*)d_ws;
    float* x    = (float*)(w8 +   0 * (size_t)MiB);
    float* a    = (float*)(w8 +   8 * (size_t)MiB);
    float* c    = (float*)(w8 +  16 * (size_t)MiB);
    float* o    = (float*)(w8 +  80 * (size_t)MiB);   // 8 MiB
    char* scratch = w8 + 88 * (size_t)MiB;            // 32 MiB
    f16* P16    = (f16*)scratch;                      // probs (32 MiB), attn phases
    f16* ffh16  = (f16*)scratch;                      // FFN hidden (16 MiB), FFN phase
    f16* cWk16s = (f16*)scratch;                      // startup only
    f16* cWv16s = (f16*)(scratch + 2 * (size_t)MiB);  // startup only
    f16* enc16  = (f16*)(scratch + 4 * (size_t)MiB);  // startup only (4 MiB)
    f16* qkv16  = (f16*)(w8 + 120 * (size_t)MiB);     // 12 MiB [2048][3072]
    f16* q16    = qkv16;                              // cross-Q reuses (4 MiB)
    f16* vt16   = (f16*)(w8 + 132 * (size_t)MiB);     // 4 MiB  [bh][64][512]
    f16* enck16 = (f16*)(w8 + 136 * (size_t)MiB);     // 4 MiB
    f16* encvt16= (f16*)(w8 + 140 * (size_t)MiB);     // 4 MiB
    f16* attn16 = (f16*)(w8 + 144 * (size_t)MiB);     // 4 MiB (also encV tmp)
    f16* x16    = (f16*)(w8 + 148 * (size_t)MiB);
    f16* a16    = (f16*)(w8 + 152 * (size_t)MiB);
    f16* c16    = (f16*)(w8 + 156 * (size_t)MiB);
    f16* mQKV16 = (f16*)(w8 + 160 * (size_t)MiB);     // 6 MiB = Wq|Wk|Wv rows
    f16* mWo16  = (f16*)(w8 + 166 * (size_t)MiB);
    f16* cWq16  = (f16*)(w8 + 168 * (size_t)MiB);
    f16* cWo16  = (f16*)(w8 + 170 * (size_t)MiB);
    f16* W116   = (f16*)(w8 + 172 * (size_t)MiB);     // 8 MiB
    f16* W216   = (f16*)(w8 + 180 * (size_t)MiB);     // 8 MiB
    f16* We16   = (f16*)(w8 + 188 * (size_t)MiB);     // 62.5 MiB

    auto conv = [&](const float* src, f16* dst, int n) {
        f32_to_f16_kernel<<<(n + 1023) / 1024, 256, 0, stream>>>(src, dst, n);
    };

    // ---- weight / encoder conversion (every call; graph-safe) ----
    const int DD = D_MODEL * D_MODEL;
    conv(mWq, mQKV16, DD);
    conv(mWk, mQKV16 + (size_t)DD, DD);
    conv(mWv, mQKV16 + 2 * (size_t)DD, DD);
    conv(mWo, mWo16, DD);
    conv(cWq, cWq16, DD); conv(cWk, cWk16s, DD); conv(cWv, cWv16s, DD); conv(cWo, cWo16, DD);
    conv(W1, W116, FFDIM * D_MODEL); conv(W2, W216, FFDIM * D_MODEL);
    conv(W_e, We16, VOCAB * D_MODEL);
    conv(enc, enc16, NTOK * D_MODEL);

    // ---- embed + posenc ----
    embed_kernel<<<SEQ, 256, 0, stream>>>(text, W_e, x, x16);

    // ---- encoder K (f16) and V^T (fixed across layers) ----
    gemm16_kernel<false, 1, 64, false><<<dim3(D_MODEL / 128, NTOK / 64), 256, 0, stream>>>(
        enc16, cWk16s, cbk, nullptr, nullptr, nullptr, enck16, NTOK, D_MODEL, D_MODEL);
    gemm16_kernel<false, 1, 64, false><<<dim3(D_MODEL / 128, NTOK / 64), 256, 0, stream>>>(
        enc16, cWv16s, cbv, nullptr, nullptr, nullptr, attn16, NTOK, D_MODEL, D_MODEL);
    vtrans_kernel<<<dim3(SEQ / 64, NBATCH * NHEAD), 256, 0, stream>>>(
        attn16, encvt16, D_MODEL, 0);

    const int BH = NBATCH * NHEAD;   // 64
    for (int layer = 0; layer < 6; layer++) {
        // --- self attention (causal), fused QKV projection ---
        gemm16_kernel<false, 1, 64, true><<<dim3(3072 / 128, NTOK / 64), 256, 0, stream>>>(
            x16, mQKV16, mbq, mbk, mbv, nullptr, qkv16, NTOK, 3072, D_MODEL);
        vtrans_kernel<<<dim3(SEQ / 64, BH), 256, 0, stream>>>(qkv16, vt16, 3072, 2048);
        attn_sm_kernel<1><<<dim3(SEQ / 64, BH), 256, 0, stream>>>(
            qkv16, qkv16, P16, 3072, 3072, 0, 1024);
        attn_av16_kernel<<<dim3(SEQ / 64, BH), 256, 0, stream>>>(P16, vt16, attn16, 1);
        gemm16_kernel<false, 0, 64, false><<<dim3(D_MODEL / 128, NTOK / 64), 256, 0, stream>>>(
            attn16, mWo16, mbo, nullptr, nullptr, o, nullptr, NTOK, D_MODEL, D_MODEL);
        add_ln_kernel<false><<<NTOK, 256, 0, stream>>>(x, o, ln_g, ln_b, a, a16);

        // --- cross attention ---
        gemm16_kernel<false, 1, 64, false><<<dim3(D_MODEL / 128, NTOK / 64), 256, 0, stream>>>(
            a16, cWq16, cbq, nullptr, nullptr, nullptr, q16, NTOK, D_MODEL, D_MODEL);
        attn_sm_kernel<0><<<dim3(SEQ / 64, BH), 256, 0, stream>>>(
            q16, enck16, P16, D_MODEL, D_MODEL, 0, 0);
        attn_av16_kernel<<<dim3(SEQ / 64, BH), 256, 0, stream>>>(P16, encvt16, attn16, 0);
        gemm16_kernel<false, 0, 64, false><<<dim3(D_MODEL / 128, NTOK / 64), 256, 0, stream>>>(
            attn16, cWo16, cbo, nullptr, nullptr, o, nullptr, NTOK, D_MODEL, D_MODEL);
        add_ln_kernel<false><<<NTOK, 256, 0, stream>>>(o, a, ln_g, ln_b, c, c16);

        // --- FFN ---
        gemm16_kernel<true, 1, 128, false><<<dim3(FFDIM / 128, NTOK / 128), 256, 0, stream>>>(
            c16, W116, b1, nullptr, nullptr, nullptr, ffh16, NTOK, FFDIM, D_MODEL);
        gemm16_kernel<false, 0, 64, false><<<dim3(D_MODEL / 128, NTOK / 64), 256, 0, stream>>>(
            ffh16, W216, b2, nullptr, nullptr, o, nullptr, NTOK, D_MODEL, FFDIM);
        if (layer < 5)
            add_ln_kernel<false><<<NTOK, 256, 0, stream>>>(c, o, ln_g, ln_b, x, x16);
        else  // last layer: x16 batch-interleaved for the logits epilogue
            add_ln_kernel<true><<<NTOK, 256, 0, stream>>>(c, o, ln_g, ln_b, x, x16);
    }

    // ---- final logits GEMM with fused axis-0 softmax epilogue ----
    gemm16_kernel<false, 2, 128, false><<<dim3(VOCAB / 128, NTOK / 128), 256, 0, stream>>>(
        x16, We16, b_out, nullptr, nullptr, out, nullptr, NTOK, VOCAB, D_MODEL);
}

// Round 3
// 2282.454 us; speedup vs baseline: 2.0312x; 1.0713x over previous
//
#include <hip/hip_runtime.h>

#define D_MODEL 1024
#define SEQ     512
#define NBATCH  4
#define NHEAD   16
#define HDIM    64
#define NTOK    2048          // NBATCH*SEQ
#define VOCAB   32000
#define FFDIM   4096
#define MiB     (1024*1024)

typedef _Float16 f16;
typedef f16   f16x8 __attribute__((ext_vector_type(8)));
typedef float f32x4 __attribute__((ext_vector_type(4)));

// async 16B global->LDS copy (direct-to-shared DMA; LDS dest must be linear
// in lane order: dst = base + lane*16)
__device__ __forceinline__ void async_cp16(f16* lds, const f16* g) {
    __builtin_amdgcn_global_load_lds(
        (const __attribute__((address_space(1))) unsigned int*)g,
        (__attribute__((address_space(3))) unsigned int*)lds, 16, 0, 0);
}

// ---------------- block reduction helper (256 threads = 4 waves) -----------
__device__ __forceinline__ float block_sum(float v, float* lds) {
    #pragma unroll
    for (int o = 1; o < 64; o <<= 1) v += __shfl_xor(v, o);
    int w = threadIdx.x >> 6;
    if ((threadIdx.x & 63) == 0) lds[w] = v;
    __syncthreads();
    v = lds[0] + lds[1] + lds[2] + lds[3];
    __syncthreads();
    return v;
}

// ---------------- fp32 -> fp16 convert -------------------------------------
__global__ __launch_bounds__(256) void f32_to_f16_kernel(
    const float* __restrict__ in, f16* __restrict__ out, int n)
{
    int i0 = blockIdx.x * 1024 + threadIdx.x;
    #pragma unroll
    for (int e = 0; e < 4; e++) {
        int i = i0 + e * 256;
        if (i < n) out[i] = (f16)in[i];
    }
}

// ---------------- embedding + sinusoidal posenc (f32 + f16 out) ------------
__global__ __launch_bounds__(256) void embed_kernel(
    const int* __restrict__ text, const float* __restrict__ We,
    float* __restrict__ X, f16* __restrict__ X16)
{
    int s = blockIdx.x;            // position 0..511
    int tid = threadIdx.x;
    int tok[NBATCH];
    #pragma unroll
    for (int b = 0; b < NBATCH; b++) tok[b] = text[b * SEQ + s];
    const float kf = 9.210340371976184f / 1024.f;   // ln(10000)/D
    #pragma unroll
    for (int e = 0; e < 4; e++) {
        int d = tid + e * 256;
        int i2 = d & ~1;
        float freq = expf(-(float)i2 * kf);
        float ang = (float)s * freq;
        float pe = (d & 1) ? cosf(ang) : sinf(ang);
        #pragma unroll
        for (int b = 0; b < NBATCH; b++) {
            float v = We[(size_t)tok[b] * D_MODEL + d] + pe;
            size_t off = (size_t)(b * SEQ + s) * D_MODEL + d;
            X[off] = v;
            X16[off] = (f16)v;
        }
    }
}

// ---------------- fp16 MFMA GEMM: C(M,N)=A(M,K)@W(N,K)^T + bias ------------
// BMx128 tile (BM = 128 or 64), BK=64, 256 threads = 4 waves (2x2), each
// wave computes (BM/2)x64.  LDS rows are 128B (8 chunks of 16B), stored with
// chunk ^= (row&7) swizzle (source pre-swizzled so global_load_lds stays
// linear) -> conflict-free ds_read_b128.
// OUTMODE: 0 = f32 out, 1 = f16 out, 2 = softmax over r (batch axis, A rows
// interleaved s*4+b) written straight to the final output.
// QKV3: bias selected from 3 pointers by col>>10 (fused QKV projection).
template<bool RELU, int OUTMODE, int BM, bool QKV3>
__global__ __launch_bounds__(256) void gemm16_kernel(
    const f16* __restrict__ A, const f16* __restrict__ W,
    const float* __restrict__ bias, const float* __restrict__ bias2,
    const float* __restrict__ bias3,
    float* __restrict__ C, f16* __restrict__ C16, int M, int N, int K)
{
    constexpr int AM = BM / 2;     // wave M span
    constexpr int TM = AM / 16;    // 16x16 tiles per wave in M
    __shared__ __align__(16) f16 As[BM * 64];
    __shared__ __align__(16) f16 Bs[128 * 64];
    const int tid  = threadIdx.x;
    const int lane = tid & 63;
    const int wv   = tid >> 6;
    const int wr   = (wv >> 1) * AM;
    const int wc   = (wv & 1) * 64;
    const int m0 = blockIdx.y * BM;
    const int n0 = blockIdx.x * 128;
    const int lm = lane & 15;
    const int lg = lane >> 4;      // 0..3 (k-group)

    f32x4 acc[TM][4] = {};

    for (int k0 = 0; k0 < K; k0 += 64) {
        #pragma unroll
        for (int e = 0; e < BM / 32; e++) {
            int s = tid + e * 256;
            int row = s >> 3, cb = s & 7;
            async_cp16(&As[s * 8],
                       &A[(size_t)(m0 + row) * K + k0 + ((cb ^ (row & 7)) * 8)]);
        }
        #pragma unroll
        for (int e = 0; e < 4; e++) {
            int s = tid + e * 256;
            int row = s >> 3, cb = s & 7;
            async_cp16(&Bs[s * 8],
                       &W[(size_t)(n0 + row) * K + k0 + ((cb ^ (row & 7)) * 8)]);
        }
        __syncthreads();
        #pragma unroll
        for (int ks = 0; ks < 2; ks++) {
            f16x8 af[TM], bfr[4];
            #pragma unroll
            for (int i = 0; i < TM; i++) {
                int arow = wr + i * 16 + lm;
                af[i] = *(const f16x8*)&As[arow * 64 + (((ks * 4 + lg) ^ (arow & 7)) * 8)];
            }
            #pragma unroll
            for (int j = 0; j < 4; j++) {
                int brow = wc + j * 16 + lm;
                bfr[j] = *(const f16x8*)&Bs[brow * 64 + (((ks * 4 + lg) ^ (brow & 7)) * 8)];
            }
            #pragma unroll
            for (int i = 0; i < TM; i++)
                #pragma unroll
                for (int j = 0; j < 4; j++)
                    acc[i][j] = __builtin_amdgcn_mfma_f32_16x16x32_f16(
                        af[i], bfr[j], acc[i][j], 0, 0, 0);
        }
        __syncthreads();
    }

    const int rq = lg * 4;
    #pragma unroll
    for (int i = 0; i < TM; i++) {
        #pragma unroll
        for (int j = 0; j < 4; j++) {
            int col = n0 + wc + j * 16 + lm;
            float bj;
            if (QKV3) {
                const float* bp = col < 1024 ? bias : (col < 2048 ? bias2 : bias3);
                bj = bp[col & 1023];
            } else {
                bj = bias[col];
            }
            if (OUTMODE == 2) {
                // rows are s*4+b (b = r): softmax over the 4 batch values
                int srow = (m0 + wr + i * 16 + rq) >> 2;
                float v[4];
                float mx = -1e30f;
                #pragma unroll
                for (int r = 0; r < 4; r++) {
                    v[r] = acc[i][j][r] + bj;
                    mx = fmaxf(mx, v[r]);
                }
                float ssum = 0.f;
                #pragma unroll
                for (int r = 0; r < 4; r++) { v[r] = expf(v[r] - mx); ssum += v[r]; }
                float inv = 1.f / ssum;
                #pragma unroll
                for (int r = 0; r < 4; r++)
                    C[((size_t)r * SEQ + srow) * N + col] = v[r] * inv;
            } else {
                #pragma unroll
                for (int r = 0; r < 4; r++) {
                    int row = m0 + wr + i * 16 + rq + r;
                    float v = acc[i][j][r] + bj;
                    if (RELU) v = fmaxf(v, 0.f);
                    if (OUTMODE == 0) C[(size_t)row * N + col] = v;
                    else              C16[(size_t)row * N + col] = (f16)v;
                }
            }
        }
    }
}

// ---------------- fully fused attention: QK^T + softmax + PV ---------------
// Per block: (64 q-rows, bh); 4 waves, wave w owns q rows w*16..w*16+15.
// Phase 1: S row (512) in registers, K double-buffered in LDS, exact softmax,
// P (f16) written to LDS (chunk-XOR swizzled).  Phase 2: O = P @ Vt with Vt
// (pre-transposed [bh][d][s]) double-buffered in LDS (aliases Q region).
// LDS: 16 KB (Q/V union) + 32 KB K dbuf + 64 KB P = 112 KB -> 1 block/CU.
template<int CAUSAL>
__global__ __launch_bounds__(256, 1) void attn_fused_kernel(
    const f16* __restrict__ Qb, const f16* __restrict__ Kb,
    const f16* __restrict__ Vt, f16* __restrict__ O16,
    int ldq, int ldk, int qoff, int koff)
{
    __shared__ __align__(16) char smem[114688];
    f16* QV = (f16*)smem;                      // Qs[64][64] / Vs[2][64][64]
    f16* Ks = (f16*)(smem + 16384);            // [2][128][64]
    f16* Ps = (f16*)(smem + 49152);            // [64][512] swizzled

    const int bh = blockIdx.y;
    const int b = bh >> 4, h = bh & 15;
    const int q0 = blockIdx.x * 64;
    const int tid  = threadIdx.x;
    const int lane = tid & 63;
    const int w    = tid >> 6;
    const int lm   = lane & 15;
    const int lg   = lane >> 4;                // 0..3
    const int nkt  = CAUSAL ? (q0 >> 7) + 1 : 4;   // 128-wide k-tiles

    const f16* Qg = Qb + (size_t)(b * SEQ + q0) * ldq + qoff + h * HDIM;
    const f16* Kg = Kb + (size_t)(b * SEQ) * ldk + koff + h * HDIM;
    const f16* Vg = Vt + (size_t)bh * HDIM * SEQ;

    // ---- stage Q (64x64) + K tile 0 (128x64), swizzled source ----
    #pragma unroll
    for (int e = 0; e < 2; e++) {
        int s = tid + e * 256;                 // 0..511
        int row = s >> 3, cb = s & 7;
        async_cp16(&QV[s * 8], &Qg[(size_t)row * ldq + ((cb ^ (row & 7)) * 8)]);
    }
    #pragma unroll
    for (int e = 0; e < 4; e++) {
        int s = tid + e * 256;                 // 0..1023
        int row = s >> 3, cb = s & 7;
        async_cp16(&Ks[s * 8], &Kg[(size_t)row * ldk + ((cb ^ (row & 7)) * 8)]);
    }
    __syncthreads();

    f16x8 af[2];
    {
        int arow = w * 16 + lm;
        af[0] = *(const f16x8*)&QV[arow * 64 + (((lg) ^ (arow & 7)) * 8)];
        af[1] = *(const f16x8*)&QV[arow * 64 + (((4 + lg) ^ (arow & 7)) * 8)];
    }

    f32x4 acc[32] = {};

    #pragma unroll
    for (int kt = 0; kt < 4; kt++) {
        if (kt < nkt) {
            if (kt + 1 < nkt) {                // prefetch next K tile
                const f16* src = Kg + (size_t)(kt + 1) * 128 * ldk;
                f16* dst = &Ks[((kt + 1) & 1) * 8192];
                #pragma unroll
                for (int e = 0; e < 4; e++) {
                    int s = tid + e * 256;
                    int row = s >> 3, cb = s & 7;
                    async_cp16(&dst[s * 8],
                               &src[(size_t)row * ldk + ((cb ^ (row & 7)) * 8)]);
                }
            }
            const f16* kb = &Ks[(kt & 1) * 8192];
            #pragma unroll
            for (int ks = 0; ks < 2; ks++)
                #pragma unroll
                for (int j = 0; j < 8; j++) {
                    int brow = j * 16 + lm;
                    f16x8 bf = *(const f16x8*)&kb[brow * 64 +
                                    (((ks * 4 + lg) ^ (brow & 7)) * 8)];
                    acc[kt * 8 + j] = __builtin_amdgcn_mfma_f32_16x16x32_f16(
                        af[ks], bf, acc[kt * 8 + j], 0, 0, 0);
                }
            if (kt + 1 < nkt) __syncthreads();
        }
    }

    // ---- exact row softmax -> P in LDS (swizzled) ----
    const int nj = nkt * 8;
    const int rq = lg * 4;
    #pragma unroll
    for (int r = 0; r < 4; r++) {
        const int ql = w * 16 + rq + r;        // local q row 0..63
        const int qq = q0 + ql;
        float mr = -1e30f;
        #pragma unroll
        for (int j = 0; j < 32; j++) {
            if (j < nj) {
                float v = acc[j][r] * 0.125f;  // 1/sqrt(64)
                if (CAUSAL && (j * 16 + lm) > qq) v = -1e30f;
                acc[j][r] = v;
                mr = fmaxf(mr, v);
            }
        }
        mr = fmaxf(mr, __shfl_xor(mr, 1));
        mr = fmaxf(mr, __shfl_xor(mr, 2));
        mr = fmaxf(mr, __shfl_xor(mr, 4));
        mr = fmaxf(mr, __shfl_xor(mr, 8));
        float sum = 0.f;
        #pragma unroll
        for (int j = 0; j < 32; j++) {
            if (j < nj) {
                float e = expf(acc[j][r] - mr);
                acc[j][r] = e;
                sum += e;
            }
        }
        sum += __shfl_xor(sum, 1);
        sum += __shfl_xor(sum, 2);
        sum += __shfl_xor(sum, 4);
        sum += __shfl_xor(sum, 8);
        float inv = 1.f / sum;
        #pragma unroll
        for (int j = 0; j < 32; j++) {
            if (j < nj) {
                int k = j * 16 + lm;
                int cs = (k >> 3) ^ (ql & 7);
                Ps[ql * 512 + cs * 8 + (k & 7)] = (f16)(acc[j][r] * inv);
            }
        }
    }

    // ---- phase 2: O = P @ Vt ----
    __syncthreads();   // all Qs reads done (Vs aliases), all P written
    const int nvt = CAUSAL ? nkt * 2 : 8;      // 64-wide k-steps
    // stage V tile 0
    #pragma unroll
    for (int e = 0; e < 2; e++) {
        int s = tid + e * 256;
        int row = s >> 3, cb = s & 7;
        async_cp16(&QV[s * 8], &Vg[(size_t)row * SEQ + ((cb ^ (row & 7)) * 8)]);
    }
    __syncthreads();

    f32x4 acc_o[4] = {};
    const int qlr = w * 16 + lm;               // A-frag row for this lane
    for (int t = 0; t < nvt; t++) {
        if (t + 1 < nvt) {                     // prefetch next V tile
            const f16* src = Vg + (t + 1) * 64;
            f16* dst = &QV[((t + 1) & 1) * 4096];
            #pragma unroll
            for (int e = 0; e < 2; e++) {
                int s = tid + e * 256;
                int row = s >> 3, cb = s & 7;
                async_cp16(&dst[s * 8],
                           &src[(size_t)row * SEQ + ((cb ^ (row & 7)) * 8)]);
            }
        }
        const f16* vb = &QV[(t & 1) * 4096];
        #pragma unroll
        for (int ks = 0; ks < 2; ks++) {
            int ck = t * 8 + ks * 4 + lg;      // P chunk index
            f16x8 ap = *(const f16x8*)&Ps[qlr * 512 + ((ck ^ (qlr & 7)) * 8)];
            #pragma unroll
            for (int jd = 0; jd < 4; jd++) {
                int vrow = jd * 16 + lm;
                f16x8 bf = *(const f16x8*)&vb[vrow * 64 +
                                (((ks * 4 + lg) ^ (vrow & 7)) * 8)];
                acc_o[jd] = __builtin_amdgcn_mfma_f32_16x16x32_f16(
                    ap, bf, acc_o[jd], 0, 0, 0);
            }
        }
        if (t + 1 < nvt) __syncthreads();
    }

    #pragma unroll
    for (int jd = 0; jd < 4; jd++)
        #pragma unroll
        for (int r = 0; r < 4; r++)
            O16[(size_t)(b * SEQ + q0 + w * 16 + rq + r) * D_MODEL
                + h * HDIM + jd * 16 + lm] = (f16)acc_o[jd][r];
}

// ---------------- V transpose: [token][ldv]@vbase+h*64 -> Vt[bh][d][s] -----
__global__ __launch_bounds__(256) void vtrans_kernel(
    const f16* __restrict__ V, f16* __restrict__ Vt, int ldv, int vbase)
{
    __shared__ __align__(16) f16 t[64][72];
    const int bh = blockIdx.y;
    const int b = bh >> 4, h = bh & 15;
    const int s0 = blockIdx.x * 64;
    const int tid = threadIdx.x;
    const int r = tid >> 3;            // 0..31
    const int c8 = (tid & 7) * 8;
    #pragma unroll
    for (int half = 0; half < 2; half++) {
        int row = r + half * 32;
        f16x8 v = *(const f16x8*)&V[(size_t)(b * SEQ + s0 + row) * ldv
                                    + vbase + h * HDIM + c8];
        #pragma unroll
        for (int j = 0; j < 8; j++) t[c8 + j][row] = v[j];
    }
    __syncthreads();
    const int d = tid >> 2;            // 0..63
    const int sblk = (tid & 3) * 16;
    f16* dst = Vt + ((size_t)bh * HDIM + d) * SEQ + s0 + sblk;
    *(f16x8*)&dst[0] = *(const f16x8*)&t[d][sblk];
    *(f16x8*)&dst[8] = *(const f16x8*)&t[d][sblk + 8];
}

// ---------------- fused residual add + LayerNorm (f32 + f16 out) -----------
// IL: write the f16 copy batch-interleaved (row' = s*4+b) for the fused
// logits+softmax epilogue.
template<bool IL>
__global__ __launch_bounds__(256) void add_ln_kernel(
    const float* __restrict__ X, const float* __restrict__ Y,
    const float* __restrict__ g, const float* __restrict__ bb,
    float* __restrict__ Out, f16* __restrict__ Out16)
{
    __shared__ float lds[4];
    int row = blockIdx.x;
    const float* xp = X + (size_t)row * D_MODEL;
    const float* yp = Y + (size_t)row * D_MODEL;
    int tid = threadIdx.x;
    float s[4];
    float lsum = 0.f;
    #pragma unroll
    for (int e = 0; e < 4; e++) {
        int d = tid + e * 256;
        s[e] = xp[d] + yp[d];
        lsum += s[e];
    }
    float mu = block_sum(lsum, lds) * (1.f / D_MODEL);
    float lv = 0.f;
    #pragma unroll
    for (int e = 0; e < 4; e++) { float t = s[e] - mu; lv += t * t; }
    float rstd = rsqrtf(block_sum(lv, lds) * (1.f / D_MODEL) + 1e-5f);
    int orow = IL ? ((row & (SEQ - 1)) * 4 + (row >> 9)) : row;
    #pragma unroll
    for (int e = 0; e < 4; e++) {
        int d = tid + e * 256;
        float v = (s[e] - mu) * rstd * g[d] + bb[d];
        Out[(size_t)row * D_MODEL + d] = v;
        Out16[(size_t)orow * D_MODEL + d] = (f16)v;
    }
}

// ===========================================================================
extern "C" void kernel_launch(void* const* d_in, const int* in_sizes, int n_in,
                              void* d_out, int out_size, void* d_ws, size_t ws_size,
                              hipStream_t stream)
{
    const int*   text = (const int*)d_in[0];
    const float* enc  = (const float*)d_in[1];
    const float* W_e  = (const float*)d_in[2];
    const float* b_out= (const float*)d_in[3];
    const float* ln_g = (const float*)d_in[4];
    const float* ln_b = (const float*)d_in[5];
    const float* W1   = (const float*)d_in[6];
    const float* b1   = (const float*)d_in[7];
    const float* W2   = (const float*)d_in[8];
    const float* b2   = (const float*)d_in[9];
    const float* mWq  = (const float*)d_in[10]; const float* mbq = (const float*)d_in[11];
    const float* mWk  = (const float*)d_in[12]; const float* mbk = (const float*)d_in[13];
    const float* mWv  = (const float*)d_in[14]; const float* mbv = (const float*)d_in[15];
    const float* mWo  = (const float*)d_in[16]; const float* mbo = (const float*)d_in[17];
    const float* cWq  = (const float*)d_in[18]; const float* cbq = (const float*)d_in[19];
    const float* cWk  = (const float*)d_in[20]; const float* cbk = (const float*)d_in[21];
    const float* cWv  = (const float*)d_in[22]; const float* cbv = (const float*)d_in[23];
    const float* cWo  = (const float*)d_in[24]; const float* cbo = (const float*)d_in[25];
    float* out = (float*)d_out;

    // ---- workspace layout ----
    char* w8 = (char*)d_ws;
    float* x    = (float*)(w8 +   0 * (size_t)MiB);
    float* a    = (float*)(w8 +   8 * (size_t)MiB);
    float* c    = (float*)(w8 +  16 * (size_t)MiB);
    float* o    = (float*)(w8 +  80 * (size_t)MiB);   // 8 MiB
    char* scratch = w8 + 88 * (size_t)MiB;            // 32 MiB
    f16* ffh16  = (f16*)scratch;                      // FFN hidden (16 MiB)
    f16* cWk16s = (f16*)scratch;                      // startup only
    f16* cWv16s = (f16*)(scratch + 2 * (size_t)MiB);  // startup only
    f16* enc16  = (f16*)(scratch + 4 * (size_t)MiB);  // startup only (4 MiB)
    f16* qkv16  = (f16*)(w8 + 120 * (size_t)MiB);     // 12 MiB [2048][3072]
    f16* q16    = qkv16;                              // cross-Q reuses (4 MiB)
    f16* vt16   = (f16*)(w8 + 132 * (size_t)MiB);     // 4 MiB  [bh][64][512]
    f16* enck16 = (f16*)(w8 + 136 * (size_t)MiB);     // 4 MiB
    f16* encvt16= (f16*)(w8 + 140 * (size_t)MiB);     // 4 MiB
    f16* attn16 = (f16*)(w8 + 144 * (size_t)MiB);     // 4 MiB (also encV tmp)
    f16* x16    = (f16*)(w8 + 148 * (size_t)MiB);
    f16* a16    = (f16*)(w8 + 152 * (size_t)MiB);
    f16* c16    = (f16*)(w8 + 156 * (size_t)MiB);
    f16* mQKV16 = (f16*)(w8 + 160 * (size_t)MiB);     // 6 MiB = Wq|Wk|Wv rows
    f16* mWo16  = (f16*)(w8 + 166 * (size_t)MiB);
    f16* cWq16  = (f16*)(w8 + 168 * (size_t)MiB);
    f16* cWo16  = (f16*)(w8 + 170 * (size_t)MiB);
    f16* W116   = (f16*)(w8 + 172 * (size_t)MiB);     // 8 MiB
    f16* W216   = (f16*)(w8 + 180 * (size_t)MiB);     // 8 MiB
    f16* We16   = (f16*)(w8 + 188 * (size_t)MiB);     // 62.5 MiB

    auto conv = [&](const float* src, f16* dst, int n) {
        f32_to_f16_kernel<<<(n + 1023) / 1024, 256, 0, stream>>>(src, dst, n);
    };

    // ---- weight / encoder conversion (every call; graph-safe) ----
    const int DD = D_MODEL * D_MODEL;
    conv(mWq, mQKV16, DD);
    conv(mWk, mQKV16 + (size_t)DD, DD);
    conv(mWv, mQKV16 + 2 * (size_t)DD, DD);
    conv(mWo, mWo16, DD);
    conv(cWq, cWq16, DD); conv(cWk, cWk16s, DD); conv(cWv, cWv16s, DD); conv(cWo, cWo16, DD);
    conv(W1, W116, FFDIM * D_MODEL); conv(W2, W216, FFDIM * D_MODEL);
    conv(W_e, We16, VOCAB * D_MODEL);
    conv(enc, enc16, NTOK * D_MODEL);

    // ---- embed + posenc ----
    embed_kernel<<<SEQ, 256, 0, stream>>>(text, W_e, x, x16);

    // ---- encoder K (f16) and V^T (fixed across layers) ----
    gemm16_kernel<false, 1, 64, false><<<dim3(D_MODEL / 128, NTOK / 64), 256, 0, stream>>>(
        enc16, cWk16s, cbk, nullptr, nullptr, nullptr, enck16, NTOK, D_MODEL, D_MODEL);
    gemm16_kernel<false, 1, 64, false><<<dim3(D_MODEL / 128, NTOK / 64), 256, 0, stream>>>(
        enc16, cWv16s, cbv, nullptr, nullptr, nullptr, attn16, NTOK, D_MODEL, D_MODEL);
    vtrans_kernel<<<dim3(SEQ / 64, NBATCH * NHEAD), 256, 0, stream>>>(
        attn16, encvt16, D_MODEL, 0);

    const int BH = NBATCH * NHEAD;   // 64
    for (int layer = 0; layer < 6; layer++) {
        // --- self attention (causal), fused QKV projection ---
        gemm16_kernel<false, 1, 64, true><<<dim3(3072 / 128, NTOK / 64), 256, 0, stream>>>(
            x16, mQKV16, mbq, mbk, mbv, nullptr, qkv16, NTOK, 3072, D_MODEL);
        vtrans_kernel<<<dim3(SEQ / 64, BH), 256, 0, stream>>>(qkv16, vt16, 3072, 2048);
        attn_fused_kernel<1><<<dim3(SEQ / 64, BH), 256, 0, stream>>>(
            qkv16, qkv16, vt16, attn16, 3072, 3072, 0, 1024);
        gemm16_kernel<false, 0, 64, false><<<dim3(D_MODEL / 128, NTOK / 64), 256, 0, stream>>>(
            attn16, mWo16, mbo, nullptr, nullptr, o, nullptr, NTOK, D_MODEL, D_MODEL);
        add_ln_kernel<false><<<NTOK, 256, 0, stream>>>(x, o, ln_g, ln_b, a, a16);

        // --- cross attention ---
        gemm16_kernel<false, 1, 64, false><<<dim3(D_MODEL / 128, NTOK / 64), 256, 0, stream>>>(
            a16, cWq16, cbq, nullptr, nullptr, nullptr, q16, NTOK, D_MODEL, D_MODEL);
        attn_fused_kernel<0><<<dim3(SEQ / 64, BH), 256, 0, stream>>>(
            q16, enck16, encvt16, attn16, D_MODEL, D_MODEL, 0, 0);
        gemm16_kernel<false, 0, 64, false><<<dim3(D_MODEL / 128, NTOK / 64), 256, 0, stream>>>(
            attn16, cWo16, cbo, nullptr, nullptr, o, nullptr, NTOK, D_MODEL, D_MODEL);
        add_ln_kernel<false><<<NTOK, 256, 0, stream>>>(o, a, ln_g, ln_b, c, c16);

        // --- FFN ---
        gemm16_kernel<true, 1, 128, false><<<dim3(FFDIM / 128, NTOK / 128), 256, 0, stream>>>(
            c16, W116, b1, nullptr, nullptr, nullptr, ffh16, NTOK, FFDIM, D_MODEL);
        gemm16_kernel<false, 0, 64, false><<<dim3(D_MODEL / 128, NTOK / 64), 256, 0, stream>>>(
            ffh16, W216, b2, nullptr, nullptr, o, nullptr, NTOK, D_MODEL, FFDIM);
        if (layer < 5)
            add_ln_kernel<false><<<NTOK, 256, 0, stream>>>(c, o, ln_g, ln_b, x, x16);
        else  // last layer: x16 batch-interleaved for the logits epilogue
            add_ln_kernel<true><<<NTOK, 256, 0, stream>>>(c, o, ln_g, ln_b, x, x16);
    }

    // ---- final logits GEMM with fused axis-0 softmax epilogue ----
    gemm16_kernel<false, 2, 128, false><<<dim3(VOCAB / 128, NTOK / 128), 256, 0, stream>>>(
        x16, We16, b_out, nullptr, nullptr, out, nullptr, NTOK, VOCAB, D_MODEL);
}